// Round 1
// baseline (433.601 us; speedup 1.0000x reference)
//
#include <hip/hip_runtime.h>

// TranslationLayer: out[b,y,x,0] = in[b, y+dyi, x-dxi, 0] if in-range else 0
// B=1024, WIN=256, C=1, fp32. Pure memory-bound shifted copy.
//
// Layout: row = b*WIN + y. Each thread handles 4 consecutive x (float4 store).
// 64 threads per row, 4 rows per 256-thread block (block never straddles b
// since WIN*WIN/4 = 16384 threads per image = 64 blocks exactly).

#define BWIN 256   // WIN
#define NB   1024  // B

__global__ __launch_bounds__(256) void translate_kernel(
    const float* __restrict__ in,
    const float* __restrict__ dx,
    const float* __restrict__ dy,
    float* __restrict__ out)
{
    const int gid = blockIdx.x * 256 + threadIdx.x;
    const int x4  = (gid & 63) << 2;   // 0,4,...,252
    const int row = gid >> 6;          // b*WIN + y
    const int y   = row & (BWIN - 1);
    const int b   = row >> 8;          // row / WIN

    // C cast truncates toward zero == jnp astype(int32)
    const int dxi = (int)dx[b];
    const int dyi = (int)dy[b];
    const int sy  = y + dyi;

    float4 v = make_float4(0.f, 0.f, 0.f, 0.f);
    if (sy >= 0 && sy < BWIN) {
        const float* __restrict__ src = in + ((size_t)b * BWIN + (size_t)sy) * BWIN;
        const int sx0 = x4 - dxi;
        if (sx0 >= 0 && sx0 + 3 < BWIN) {
            // fast path: all 4 in range (true for all but ~2 threads/row)
            v.x = src[sx0 + 0];
            v.y = src[sx0 + 1];
            v.z = src[sx0 + 2];
            v.w = src[sx0 + 3];
        } else {
            float tmp[4];
#pragma unroll
            for (int j = 0; j < 4; ++j) {
                const int sx = sx0 + j;
                tmp[j] = (sx >= 0 && sx < BWIN) ? src[sx] : 0.f;
            }
            v = make_float4(tmp[0], tmp[1], tmp[2], tmp[3]);
        }
    }

    float4* outp = (float4*)(out + (size_t)row * BWIN + x4);
    *outp = v;
}

extern "C" void kernel_launch(void* const* d_in, const int* in_sizes, int n_in,
                              void* d_out, int out_size, void* d_ws, size_t ws_size,
                              hipStream_t stream) {
    const float* in = (const float*)d_in[0];
    const float* dx = (const float*)d_in[1];
    const float* dy = (const float*)d_in[2];
    float* out = (float*)d_out;

    // total threads = B*WIN*WIN/4 = 16,777,216 -> 65536 blocks of 256
    const int total_threads = NB * BWIN * BWIN / 4;
    const int blocks = total_threads / 256;
    translate_kernel<<<blocks, 256, 0, stream>>>(in, dx, dy, out);
}

// Round 2
// 420.645 us; speedup vs baseline: 1.0308x; 1.0308x over previous
//
#include <hip/hip_runtime.h>

// TranslationLayer: out[b,y,x] = in[b, y+dyi[b], x-dxi[b]] if in-range else 0
// B=1024, WIN=256, C=1, fp32. Pure memory-bound shifted row copy.
//
// Key insight vs R0: dxi is uniform per image (and each 256-thread block maps
// to exactly 4 rows of ONE image), so the sub-float4 shift sh = (-dxi) & 3 is
// wave-uniform. Read via two ALIGNED lane-contiguous float4 chunks and blend
// in registers (compile-time register picks per uniform branch). Chunk1
// overlaps neighbor lane's chunk0 -> L1 hit, no extra HBM traffic.

#define WIN 256
#define NB  1024

__global__ __launch_bounds__(256) void translate_kernel(
    const float* __restrict__ in,
    const float* __restrict__ dx,
    const float* __restrict__ dy,
    float* __restrict__ out)
{
    const int gid   = blockIdx.x * 256 + threadIdx.x;
    const int lane4 = gid & 63;        // which float4 within the row
    const int row   = gid >> 6;        // b*WIN + y
    const int y     = row & (WIN - 1);
    const int b     = row >> 8;

    // dx[b]/dy[b] uniform across the block -> force into SGPRs
    const int dxi = __builtin_amdgcn_readfirstlane((int)dx[b]);  // trunc == astype(int32)
    const int dyi = __builtin_amdgcn_readfirstlane((int)dy[b]);
    const int sy  = y + dyi;

    float4 v = make_float4(0.f, 0.f, 0.f, 0.f);

    if (sy >= 0 && sy < WIN) {                 // scalar branch (uniform per 4-row group? no: per lane-row)
        const float* __restrict__ src = in + (((size_t)b << 8) + (size_t)sy) * WIN;
        const int x4   = lane4 << 2;
        const int sx0  = x4 - dxi;             // first source column
        const int sh   = sx0 & 3;              // wave-uniform sub-vector shift
        const int base = sx0 - sh;             // 16B-aligned, lane-contiguous

        if (sh == 0) {
            if (base >= 0 && base <= WIN - 4) {
                v = *(const float4*)(src + base);
            } else {                            // edge lane: per-element
#pragma unroll
                for (int j = 0; j < 4; ++j) {
                    const int sx = sx0 + j;
                    ((float*)&v)[j] = (sx >= 0 && sx < WIN) ? src[sx] : 0.f;
                }
            }
        } else {
            if (base >= 0 && base + 8 <= WIN) {
                const float4 c0 = *(const float4*)(src + base);
                const float4 c1 = *(const float4*)(src + base + 4);
                if (sh == 1)      v = make_float4(c0.y, c0.z, c0.w, c1.x);
                else if (sh == 2) v = make_float4(c0.z, c0.w, c1.x, c1.y);
                else              v = make_float4(c0.w, c1.x, c1.y, c1.z);
            } else {                            // edge lanes (1-2 per wave)
#pragma unroll
                for (int j = 0; j < 4; ++j) {
                    const int sx = sx0 + j;
                    ((float*)&v)[j] = (sx >= 0 && sx < WIN) ? src[sx] : 0.f;
                }
            }
        }
    }

    *(float4*)(out + ((size_t)row << 8) + (lane4 << 2)) = v;
}

extern "C" void kernel_launch(void* const* d_in, const int* in_sizes, int n_in,
                              void* d_out, int out_size, void* d_ws, size_t ws_size,
                              hipStream_t stream) {
    const float* in = (const float*)d_in[0];
    const float* dx = (const float*)d_in[1];
    const float* dy = (const float*)d_in[2];
    float* out = (float*)d_out;

    const int total_threads = NB * WIN * WIN / 4;   // 16,777,216
    const int blocks = total_threads / 256;         // 65,536
    translate_kernel<<<blocks, 256, 0, stream>>>(in, dx, dy, out);
}